// Round 12
// baseline (3446.277 us; speedup 1.0000x reference)
//
#include <hip/hip_runtime.h>

typedef unsigned short u16;
typedef unsigned int u32;
typedef unsigned long long u64;

#define NBLK 256

__device__ __forceinline__ float b2f(u16 u) {
    u32 i = ((u32)u) << 16;
    return __builtin_bit_cast(float, i);
}
__device__ __forceinline__ u16 f2b(float f) {
    u32 b = __builtin_bit_cast(u32, f);
    b += 0x7FFFu + ((b >> 16) & 1u);   // RNE
    return (u16)(b >> 16);
}
__device__ __forceinline__ float sigm(float x) {
    return 1.f / (1.f + __expf(-x));
}
__device__ __forceinline__ float tanh_fast(float x) {
    float a = fabsf(x);
    float e = __expf(-2.f * a);            // in (0,1], never inf
    float r = (1.f - e) / (1.f + e);
    return copysignf(r, x);
}

// ---------------------------------------------------------------------------
// Kernel A (r8 structure + W-row prefetch rotation): grid (512, 33), blk 256.
// bx<256 -> in-phase, else out-phase. Xp layout [t][wg][32], slot =
// wg*32 + g*8 + j for row r = g*2048 + wg*8 + j.
// ---------------------------------------------------------------------------
__global__ void __launch_bounds__(256)
xproj_kernel(const float* __restrict__ embed, const float* __restrict__ eos,
             const int* __restrict__ seqA, const int* __restrict__ seqB,
             const float* __restrict__ WA, const float* __restrict__ WB,
             const float* __restrict__ bA, const float* __restrict__ bB,
             float* __restrict__ XpA, float* __restrict__ XpB)
{
    __shared__ float xs[8][512];
    const int which = blockIdx.x >> 8;
    const int bx = blockIdx.x & 255;
    const int* __restrict__ seq  = which ? seqB : seqA;
    const float* __restrict__ W  = which ? WB : WA;
    const float* __restrict__ bias = which ? bB : bA;
    float* __restrict__ Xp = which ? XpB : XpA;

    const int tid = threadIdx.x;
    const int t0 = blockIdx.y * 8;
    const int nt = min(8, 257 - t0);

    for (int idx = tid; idx < nt * 512; idx += 256) {
        int tt = idx >> 9, col = idx & 511;
        int t = t0 + tt;
        xs[tt][col] = (t < 256) ? embed[(size_t)seq[t] * 512 + col] : eos[col];
    }
    __syncthreads();

    const int lane = tid & 63;
    const int wv = tid >> 6;

    float xr[8][8];
#pragma unroll
    for (int tt = 0; tt < 8; ++tt) {
        *(float4*)&xr[tt][0] = *(const float4*)&xs[tt][lane * 8];
        *(float4*)&xr[tt][4] = *(const float4*)&xs[tt][lane * 8 + 4];
    }

    float wf[8];
    {
        const int r = bx * 32 + wv * 8;
        *(float4*)&wf[0] = *(const float4*)&W[(size_t)r * 512 + lane * 8];
        *(float4*)&wf[4] = *(const float4*)&W[(size_t)r * 512 + lane * 8 + 4];
    }
#pragma unroll 1
    for (int rr = 0; rr < 8; ++rr) {
        const int r = bx * 32 + wv * 8 + rr;
        float wfn[8];
        if (rr < 7) {   // prefetch next row while computing current
            *(float4*)&wfn[0] = *(const float4*)&W[(size_t)(r + 1) * 512 + lane * 8];
            *(float4*)&wfn[4] = *(const float4*)&W[(size_t)(r + 1) * 512 + lane * 8 + 4];
        }
        float acc[8];
#pragma unroll
        for (int tt = 0; tt < 8; tt++) {
            float a = 0.f;
#pragma unroll
            for (int j = 0; j < 8; j++) a = fmaf(wf[j], xr[tt][j], a);
            acc[tt] = a;
        }
#pragma unroll
        for (int tt = 0; tt < 8; tt++) {
            float a = acc[tt];
#pragma unroll
            for (int off = 32; off > 0; off >>= 1) a += __shfl_xor(a, off, 64);
            if (lane == 0 && tt < nt) {
                int g = r >> 11, rem = r & 2047, wgi = rem >> 3, j = rem & 7;
                Xp[(size_t)(t0 + tt) * 8192 + (wgi << 5) + (g << 3) + j] = a + bias[r];
            }
        }
        if (rr < 7) {
#pragma unroll
            for (int j = 0; j < 8; ++j) wf[j] = wfn[j];
        }
    }
}

// ---------------------------------------------------------------------------
// Kernel B: persistent LSTM, barrier-free across blocks. 256 WGs x 512 thr.
// Whh in fp32 registers w[4][32] (lane owns cols {256q+4*lane+j}).
// h exchange: hseq64[t][512] u64 granules (4 bf16 each), 0xFF..F sentinel.
// Producer: lanes 0-1 store ONE u64 each (all-or-nothing granule).
// Consumer: each lane polls ITS OWN 8 granules (i = 64q+lane) straight into
// registers -- no LDS staging, no barrier #1. All waves poll the same 512
// granules, so straggler compaction is preserved without a barrier.
// One __syncthreads per step (gsum). Staging branch AFTER the poll so its
// 64 in-flight W loads never serialize into the poll (in-order VMEM).
// ---------------------------------------------------------------------------
__global__ void __launch_bounds__(512, 1)
rnn_coop(const float* __restrict__ WhhA, const float* __restrict__ WhhB,
         const float* __restrict__ pWih, const float* __restrict__ pWhh,
         const float* __restrict__ pB,
         const float* __restrict__ Xp0, const float* __restrict__ Xp1,
         u64* __restrict__ hseq64, float* __restrict__ out)
{
    __shared__ float gsum[32];

    const int wg = blockIdx.x;
    const int tid = threadIdx.x;
    const int lane = tid & 63;
    const int wv = tid >> 6;

    float w[4][32];        // fp32 Whh slice: rows rl=4*wv+rr, 32 cols/lane
    float c_reg = 0.f;     // valid on wave 0
    float xp2 = 0.f;       // phase-2 gate input (pB), wave0 lanes 0-31

    if (tid < 32) gsum[tid] = 0.f;

    float xp_cur = 0.f, xp_nxt = 0.f;
    if (wv == 0 && lane < 32)
        xp_cur = Xp0[(wg << 5) + lane];   // t=0, phase 0

    for (int t = 0; t < 524; ++t) {
        const int phase = (t < 257) ? 0 : (t < 514) ? 1 : 2;

        // ---- poll own 8 granules straight into registers ----
        u64 v[8];
        if (t > 0) {
            const u64* src = hseq64 + (size_t)(t - 1) * 512;
#pragma unroll
            for (int q = 0; q < 8; ++q)
                v[q] = __hip_atomic_load(&src[(q << 6) + lane], __ATOMIC_RELAXED,
                                         __HIP_MEMORY_SCOPE_AGENT);
            for (;;) {
                u32 m = 0;
#pragma unroll
                for (int q = 0; q < 8; ++q)
                    if (v[q] == ~0ull) m |= 1u << q;
                if (!__any(m != 0)) break;
#pragma unroll
                for (int q = 0; q < 8; ++q)
                    if (m & (1u << q))
                        v[q] = __hip_atomic_load(&src[(q << 6) + lane],
                                                 __ATOMIC_RELAXED,
                                                 __HIP_MEMORY_SCOPE_AGENT);
            }
        }

        // ---- weight staging AFTER the poll (one-time per phase) ----
        if (t == 0 || t == 257 || t == 514) {
            if (phase < 2) {
                const float* Ws = phase ? WhhB : WhhA;
#pragma unroll
                for (int rr = 0; rr < 4; ++rr) {
                    int rl = (wv << 2) + rr;
                    const float* Wr = Ws + (size_t)(((rl >> 3) << 11) + (wg << 3) + (rl & 7)) * 2048;
#pragma unroll
                    for (int q = 0; q < 8; ++q)
                        *(float4*)&w[rr][q * 4] = *(const float4*)&Wr[(q << 8) + (lane << 2)];
                }
            } else {
#pragma unroll
                for (int rr = 0; rr < 4; ++rr) {
                    int rl = (wv << 2) + rr;
                    size_t off = (size_t)(((rl >> 3) << 11) + (wg << 3) + (rl & 7)) * 2048;
#pragma unroll
                    for (int q = 0; q < 8; ++q) {
                        float4 a = *(const float4*)&pWih[off + (q << 8) + (lane << 2)];
                        float4 b = *(const float4*)&pWhh[off + (q << 8) + (lane << 2)];
                        float4 s;
                        s.x = a.x + b.x; s.y = a.y + b.y;
                        s.z = a.z + b.z; s.w = a.w + b.w;
                        *(float4*)&w[rr][q * 4] = s;
                    }
                }
                if (wv == 0 && lane < 32)
                    xp2 = pB[((lane >> 3) << 11) + (wg << 3) + (lane & 7)];
            }
        }

        // next step's xp load: issued after the poll, consumed next tail
        if (wv == 0 && lane < 32 && t < 523) {
            const int tn = t + 1;
            if (tn < 257)       xp_nxt = Xp0[(size_t)tn * 8192 + (wg << 5) + lane];
            else if (tn < 514)  xp_nxt = Xp1[(size_t)(tn - 257) * 8192 + (wg << 5) + lane];
        }

        if (t > 0) {
            float a0 = 0.f, a1 = 0.f, a2 = 0.f, a3 = 0.f;
#pragma unroll
            for (int q = 0; q < 8; ++q) {
                const u64 a = v[q];
                const float h0 = b2f((u16)a);
                const float h1 = b2f((u16)(a >> 16));
                const float h2v = b2f((u16)(a >> 32));
                const float h3 = b2f((u16)(a >> 48));
                a0 = fmaf(w[0][q * 4 + 0], h0, a0);
                a1 = fmaf(w[1][q * 4 + 0], h0, a1);
                a2 = fmaf(w[2][q * 4 + 0], h0, a2);
                a3 = fmaf(w[3][q * 4 + 0], h0, a3);
                a0 = fmaf(w[0][q * 4 + 1], h1, a0);
                a1 = fmaf(w[1][q * 4 + 1], h1, a1);
                a2 = fmaf(w[2][q * 4 + 1], h1, a2);
                a3 = fmaf(w[3][q * 4 + 1], h1, a3);
                a0 = fmaf(w[0][q * 4 + 2], h2v, a0);
                a1 = fmaf(w[1][q * 4 + 2], h2v, a1);
                a2 = fmaf(w[2][q * 4 + 2], h2v, a2);
                a3 = fmaf(w[3][q * 4 + 2], h2v, a3);
                a0 = fmaf(w[0][q * 4 + 3], h3, a0);
                a1 = fmaf(w[1][q * 4 + 3], h3, a1);
                a2 = fmaf(w[2][q * 4 + 3], h3, a2);
                a3 = fmaf(w[3][q * 4 + 3], h3, a3);
            }
#pragma unroll
            for (int off = 32; off > 0; off >>= 1) {
                a0 += __shfl_xor(a0, off, 64);
                a1 += __shfl_xor(a1, off, 64);
                a2 += __shfl_xor(a2, off, 64);
                a3 += __shfl_xor(a3, off, 64);
            }
            if (lane == 0) {
                const int rl = wv << 2;
                gsum[rl]     = a0;
                gsum[rl + 1] = a1;
                gsum[rl + 2] = a2;
                gsum[rl + 3] = a3;
            }
        }
        __syncthreads();

        if (wv == 0) {
            // 32 parallel activations (lanes 0-31); lanes >=32 compute garbage
            float xpv = (phase < 2) ? xp_cur : xp2;
            float tot = xpv + gsum[lane & 31];
            float act = ((lane >> 3) == 2) ? tanh_fast(tot) : sigm(tot);
            const int j = lane & 7;
            float fi = __shfl(act, j, 64);        // gate i
            float ff = __shfl(act, 8 + j, 64);    // gate f
            float fg = __shfl(act, 16 + j, 64);   // gate g~
            float fo = __shfl(act, 24 + j, 64);   // gate o
            c_reg = ff * c_reg + fi * fg;
            float h2 = fo * tanh_fast(c_reg);
            u32 hb = (u32)f2b(h2);
            // lanes 0,1 pack 4 bf16 each (h indices 4L..4L+3) into ONE u64
            const int base = (lane & 1) << 2;
            u32 b0 = (u32)__shfl((int)hb, base + 0, 64) & 0xFFFFu;
            u32 b1 = (u32)__shfl((int)hb, base + 1, 64) & 0xFFFFu;
            u32 b2 = (u32)__shfl((int)hb, base + 2, 64) & 0xFFFFu;
            u32 b3 = (u32)__shfl((int)hb, base + 3, 64) & 0xFFFFu;
            u64 pk = (u64)(b0 | (b1 << 16)) | (((u64)(b2 | (b3 << 16))) << 32);
            if (lane < 2)
                __hip_atomic_store(&hseq64[(size_t)t * 512 + (wg << 1) + lane], pk,
                                   __ATOMIC_RELAXED, __HIP_MEMORY_SCOPE_AGENT);
            if (phase == 2 && lane < 8)
                out[(size_t)(t - 514) * 2048 + (wg << 3) + lane] = h2;
        }
        xp_cur = xp_nxt;
        // no inter-block barrier: data arrival is the sync
    }
}

// ---------------------------------------------------------------------------
extern "C" void kernel_launch(void* const* d_in, const int* in_sizes, int n_in,
                              void* d_out, int out_size, void* d_ws, size_t ws_size,
                              hipStream_t stream) {
    const int*   in_seq   = (const int*)d_in[0];
    const int*   out_seq  = (const int*)d_in[1];
    const float* embed    = (const float*)d_in[2];
    const float* eos      = (const float*)d_in[3];
    const float* in_Wih   = (const float*)d_in[4];
    const float* in_Whh   = (const float*)d_in[5];
    const float* in_b     = (const float*)d_in[6];
    const float* out_Wih  = (const float*)d_in[7];
    const float* out_Whh  = (const float*)d_in[8];
    const float* out_b    = (const float*)d_in[9];
    const float* pg_Wih   = (const float*)d_in[10];
    const float* pg_Whh   = (const float*)d_in[11];
    const float* pg_b     = (const float*)d_in[12];

    float* Xp0    = (float*)d_ws;                      // 257*8192 fp32
    float* Xp1    = Xp0 + (size_t)257 * 8192;          // 257*8192 fp32
    u64*   hseq64 = (u64*)(Xp1 + (size_t)257 * 8192);  // 524*512 u64

    // bf16 NaN sentinel (all-ones u64 granule); fresh region per step
    hipMemsetAsync(hseq64, 0xFF, (size_t)524 * 512 * sizeof(u64), stream);

    dim3 g1(512, 33), b1(256);
    hipLaunchKernelGGL(xproj_kernel, g1, b1, 0, stream, embed, eos,
                       in_seq, out_seq, in_Wih, out_Wih, in_b, out_b, Xp0, Xp1);

    float* out = (float*)d_out;
    void* args[] = { (void*)&in_Whh, (void*)&out_Whh, (void*)&pg_Wih, (void*)&pg_Whh,
                     (void*)&pg_b, (void*)&Xp0, (void*)&Xp1, (void*)&hseq64, (void*)&out };
    hipLaunchCooperativeKernel((const void*)rnn_coop, dim3(NBLK), dim3(512),
                               args, 0, stream);
}

// Round 14
// 1967.816 us; speedup vs baseline: 1.7513x; 1.7513x over previous
//
#include <hip/hip_runtime.h>

typedef unsigned short u16;
typedef unsigned int u32;
typedef unsigned long long u64;

#define NBLK 256

__device__ __forceinline__ float b2f(u16 u) {
    u32 i = ((u32)u) << 16;
    return __builtin_bit_cast(float, i);
}
__device__ __forceinline__ u16 f2b(float f) {
    u32 b = __builtin_bit_cast(u32, f);
    b += 0x7FFFu + ((b >> 16) & 1u);   // RNE
    return (u16)(b >> 16);
}
__device__ __forceinline__ float sigm(float x) {
    return 1.f / (1.f + __expf(-x));
}
__device__ __forceinline__ float tanh_fast(float x) {
    float a = fabsf(x);
    float e = __expf(-2.f * a);            // in (0,1], never inf
    float r = (1.f - e) / (1.f + e);
    return copysignf(r, x);
}

// ---------------------------------------------------------------------------
// Kernel A — W-STATIONARY xproj. grid (512), block 256 (2 blocks/CU).
// Block bx: which = bx>>8 (in/out phase), slice = bx&255 -> 32 rows held in
// REGISTERS (w[8][8]/lane, ~90 VGPR total), x-rows staged 8-at-a-time in
// 16KB LDS, loop over all 33 t-groups. W is read from HBM exactly once.
// Xp layout [t][wg][32], slot = wg*32 + g*8 + j for row r = g*2048+wg*8+j.
// ---------------------------------------------------------------------------
__global__ void __launch_bounds__(256)
xproj_kernel(const float* __restrict__ embed, const float* __restrict__ eos,
             const int* __restrict__ seqA, const int* __restrict__ seqB,
             const float* __restrict__ WA, const float* __restrict__ WB,
             const float* __restrict__ bA, const float* __restrict__ bB,
             float* __restrict__ XpA, float* __restrict__ XpB)
{
    __shared__ __align__(16) float xs[8][512];
    const int which = blockIdx.x >> 8;
    const int bx = blockIdx.x & 255;
    const int* __restrict__ seq  = which ? seqB : seqA;
    const float* __restrict__ W  = which ? WB : WA;
    const float* __restrict__ bias = which ? bB : bA;
    float* __restrict__ Xp = which ? XpB : XpA;

    const int tid = threadIdx.x;
    const int lane = tid & 63;
    const int wv = tid >> 6;

    // 8 rows per wave, held in registers for the whole kernel
    float w[8][8];
    float breg[8];
    int slot[8];
#pragma unroll
    for (int rr = 0; rr < 8; ++rr) {
        const int r = bx * 32 + wv * 8 + rr;
        *(float4*)&w[rr][0] = *(const float4*)&W[(size_t)r * 512 + (lane << 2)];
        *(float4*)&w[rr][4] = *(const float4*)&W[(size_t)r * 512 + 256 + (lane << 2)];
        breg[rr] = bias[r];
        int g = r >> 11, rem = r & 2047;
        slot[rr] = ((rem >> 3) << 5) + (g << 3) + (rem & 7);
    }

    for (int grp = 0; grp < 33; ++grp) {
        const int t0 = grp * 8;
        const int nt = min(8, 257 - t0);
        for (int idx = tid; idx < nt * 512; idx += 256) {
            int tt = idx >> 9, col = idx & 511;
            int t = t0 + tt;
            xs[tt][col] = (t < 256) ? embed[(size_t)seq[t] * 512 + col] : eos[col];
        }
        __syncthreads();

#pragma unroll 1
        for (int tt = 0; tt < 8; ++tt) {
            float xt[8];
            *(float4*)&xt[0] = *(const float4*)&xs[tt][(lane << 2)];
            *(float4*)&xt[4] = *(const float4*)&xs[tt][256 + (lane << 2)];
            float a[8];
#pragma unroll
            for (int rr = 0; rr < 8; ++rr) {
                float s = 0.f;
#pragma unroll
                for (int j = 0; j < 8; ++j) s = fmaf(w[rr][j], xt[j], s);
                a[rr] = s;
            }
#pragma unroll
            for (int off = 32; off > 0; off >>= 1) {
#pragma unroll
                for (int rr = 0; rr < 8; ++rr)
                    a[rr] += __shfl_xor(a[rr], off, 64);
            }
            if (lane == 0 && tt < nt) {
                float* dst = Xp + (size_t)(t0 + tt) * 8192;
#pragma unroll
                for (int rr = 0; rr < 8; ++rr)
                    dst[slot[rr]] = a[rr] + breg[rr];
            }
        }
        __syncthreads();   // protect xs before next overwrite
    }
}

// ---------------------------------------------------------------------------
// Kernel B: persistent LSTM (round-8 champion, VERBATIM). 256 WGs x 512 thr.
// Whh in fp32 registers w[4][32]; h exchange bf16-packed data-is-the-flag
// (poll hseqB[t-1] vs 0xFFFF sentinel); xp double-buffered off the detect
// path; tail on wave 0; h store lanes 0-3 (16B coalesced).
// ---------------------------------------------------------------------------
__global__ void __launch_bounds__(512, 1)
rnn_coop(const float* __restrict__ WhhA, const float* __restrict__ WhhB,
         const float* __restrict__ pWih, const float* __restrict__ pWhh,
         const float* __restrict__ pB,
         const float* __restrict__ Xp0, const float* __restrict__ Xp1,
         u32* __restrict__ hseqB, float* __restrict__ out)
{
    __shared__ __align__(16) float hs[2048];   // 8KB staged fp32 h
    __shared__ float gsum[32];

    const int wg = blockIdx.x;
    const int tid = threadIdx.x;
    const int lane = tid & 63;
    const int wv = tid >> 6;

    float w[4][32];        // fp32 weight slice: rows rl=4*wv+rr, 32 cols/lane
    float c_reg = 0.f;     // valid on lanes 0-7 of wave 0

    if (tid < 32) gsum[tid] = 0.f;

    float xp_cur = 0.f, xp_nxt = 0.f;
    if (wv == 0 && lane < 32)
        xp_cur = Xp0[(size_t)0 * 8192 + (wg << 5) + lane];   // t=0, phase 0

    for (int t = 0; t < 524; ++t) {
        const int phase = (t < 257) ? 0 : (t < 514) ? 1 : 2;

        if (t == 0 || t == 257 || t == 514) {
            if (phase < 2) {
                const float* Ws = phase ? WhhB : WhhA;
#pragma unroll
                for (int rr = 0; rr < 4; ++rr) {
                    int rl = (wv << 2) + rr;
                    const float* Wr = Ws + (size_t)(((rl >> 3) << 11) + (wg << 3) + (rl & 7)) * 2048;
#pragma unroll
                    for (int q = 0; q < 8; ++q)
                        *(float4*)&w[rr][q * 4] = *(const float4*)&Wr[(q << 8) + (lane << 2)];
                }
            } else {
#pragma unroll
                for (int rr = 0; rr < 4; ++rr) {
                    int rl = (wv << 2) + rr;
                    size_t off = (size_t)(((rl >> 3) << 11) + (wg << 3) + (rl & 7)) * 2048;
#pragma unroll
                    for (int q = 0; q < 8; ++q) {
                        float4 a = *(const float4*)&pWih[off + (q << 8) + (lane << 2)];
                        float4 b = *(const float4*)&pWhh[off + (q << 8) + (lane << 2)];
                        float4 s;
                        s.x = a.x + b.x; s.y = a.y + b.y;
                        s.z = a.z + b.z; s.w = a.w + b.w;
                        *(float4*)&w[rr][q * 4] = s;
                    }
                }
            }
        }

        if (t > 0) {
            // poll own u64 (4 bf16) of hseqB[t-1]; sentinel 0xFFFF per u16.
            // Producer writes u32 granules, so per-u16 checks are torn-safe.
            const u64* src = (const u64*)hseqB + (size_t)(t - 1) * 512 + tid;
            u64 a = __hip_atomic_load(src, __ATOMIC_RELAXED, __HIP_MEMORY_SCOPE_AGENT);
            while ((u16)a == 0xFFFFu || (u16)(a >> 16) == 0xFFFFu ||
                   (u16)(a >> 32) == 0xFFFFu || (u16)(a >> 48) == 0xFFFFu) {
                __builtin_amdgcn_s_sleep(1);
                a = __hip_atomic_load(src, __ATOMIC_RELAXED, __HIP_MEMORY_SCOPE_AGENT);
            }
            float4 hv;
            hv.x = b2f((u16)a);         hv.y = b2f((u16)(a >> 16));
            hv.z = b2f((u16)(a >> 32)); hv.w = b2f((u16)(a >> 48));
            *(float4*)&hs[tid << 2] = hv;       // 16B/lane, conflict-free
        }
        __syncthreads();

        // issue NEXT step's xp load here: covered by dot+reduce, and the
        // poll loop above never waits on it (nothing outstanding at poll)
        if (wv == 0 && lane < 32 && t < 523) {
            const int tn = t + 1;
            if (tn < 257)       xp_nxt = Xp0[(size_t)tn * 8192 + (wg << 5) + lane];
            else if (tn < 514)  xp_nxt = Xp1[(size_t)(tn - 257) * 8192 + (wg << 5) + lane];
            else                xp_nxt = pB[((lane >> 3) << 11) + (wg << 3) + (lane & 7)];
        }

        if (t > 0) {
            float a0 = 0.f, a1 = 0.f, a2 = 0.f, a3 = 0.f;
#pragma unroll
            for (int q = 0; q < 8; ++q) {
                float4 hv = *(const float4*)&hs[(q << 8) + (lane << 2)];
#pragma unroll
                for (int j = 0; j < 4; ++j) {
                    float h = ((const float*)&hv)[j];
                    a0 = fmaf(w[0][q * 4 + j], h, a0);
                    a1 = fmaf(w[1][q * 4 + j], h, a1);
                    a2 = fmaf(w[2][q * 4 + j], h, a2);
                    a3 = fmaf(w[3][q * 4 + j], h, a3);
                }
            }
#pragma unroll
            for (int off = 32; off > 0; off >>= 1) {
                a0 += __shfl_xor(a0, off, 64);
                a1 += __shfl_xor(a1, off, 64);
                a2 += __shfl_xor(a2, off, 64);
                a3 += __shfl_xor(a3, off, 64);
            }
            if (lane == 0) {
                const int rl = wv << 2;
                gsum[rl]     = a0;
                gsum[rl + 1] = a1;
                gsum[rl + 2] = a2;
                gsum[rl + 3] = a3;
            }
        }
        __syncthreads();

        if (wv == 0) {
            // 32 parallel activations (lanes 0-31); lanes >=32 compute garbage
            float tot = xp_cur + gsum[lane & 31];
            float act = ((lane >> 3) == 2) ? tanh_fast(tot) : sigm(tot);
            const int j = lane & 7;
            float fi = __shfl(act, j, 64);        // gate i
            float ff = __shfl(act, 8 + j, 64);    // gate f
            float fg = __shfl(act, 16 + j, 64);   // gate g~
            float fo = __shfl(act, 24 + j, 64);   // gate o
            c_reg = ff * c_reg + fi * fg;
            float h2 = fo * tanh_fast(c_reg);
            u32 hb = (u32)f2b(h2);
            u32 lo = (u32)__shfl((int)hb, (lane & 3) * 2, 64);
            u32 hi = (u32)__shfl((int)hb, (lane & 3) * 2 + 1, 64);
            if (lane < 4)
                __hip_atomic_store(&hseqB[(size_t)t * 1024 + (wg << 2) + lane],
                                   (hi << 16) | lo,
                                   __ATOMIC_RELAXED, __HIP_MEMORY_SCOPE_AGENT);
            if (phase == 2 && lane < 8)
                out[(size_t)(t - 514) * 2048 + (wg << 3) + lane] = h2;
        }
        xp_cur = xp_nxt;
        // no inter-block barrier: data arrival is the sync
    }
}

// ---------------------------------------------------------------------------
extern "C" void kernel_launch(void* const* d_in, const int* in_sizes, int n_in,
                              void* d_out, int out_size, void* d_ws, size_t ws_size,
                              hipStream_t stream) {
    const int*   in_seq   = (const int*)d_in[0];
    const int*   out_seq  = (const int*)d_in[1];
    const float* embed    = (const float*)d_in[2];
    const float* eos      = (const float*)d_in[3];
    const float* in_Wih   = (const float*)d_in[4];
    const float* in_Whh   = (const float*)d_in[5];
    const float* in_b     = (const float*)d_in[6];
    const float* out_Wih  = (const float*)d_in[7];
    const float* out_Whh  = (const float*)d_in[8];
    const float* out_b    = (const float*)d_in[9];
    const float* pg_Wih   = (const float*)d_in[10];
    const float* pg_Whh   = (const float*)d_in[11];
    const float* pg_b     = (const float*)d_in[12];

    float* Xp0   = (float*)d_ws;                       // 257*8192 fp32
    float* Xp1   = Xp0 + (size_t)257 * 8192;           // 257*8192 fp32
    u32*   hseqB = (u32*)(Xp1 + (size_t)257 * 8192);   // 524*1024 u32 (bf16 x2)

    // bf16 NaN sentinel 0xFFFF; fresh region per step -> no reuse races
    hipMemsetAsync(hseqB, 0xFF, (size_t)524 * 1024 * sizeof(u32), stream);

    hipLaunchKernelGGL(xproj_kernel, dim3(512), dim3(256), 0, stream,
                       embed, eos, in_seq, out_seq,
                       in_Wih, out_Wih, in_b, out_b, Xp0, Xp1);

    float* out = (float*)d_out;
    void* args[] = { (void*)&in_Whh, (void*)&out_Whh, (void*)&pg_Wih, (void*)&pg_Whh,
                     (void*)&pg_b, (void*)&Xp0, (void*)&Xp1, (void*)&hseqB, (void*)&out };
    hipLaunchCooperativeKernel((const void*)rnn_coop, dim3(NBLK), dim3(512),
                               args, 0, stream);
}